// Round 3
// baseline (246.459 us; speedup 1.0000x reference)
//
#include <hip/hip_runtime.h>
#include <hip/hip_bf16.h>
#include <hip/hip_fp16.h>

#define BSZ 2
#define CIN 32
#define COUT 64
#define DD_ 8
#define HH_ 48
#define WW_ 48
#define KK 27
#define HWs (HH_*WW_)
#define DHW (DD_*HH_*WW_)
#define CP 49   // padded C-reduce row stride (floats)

typedef __attribute__((ext_vector_type(8))) short short8v;
typedef __attribute__((ext_vector_type(4))) float f32x4;

// Pack weight (Cout, Cin, K) fp32 -> bf16 A-fragments in lane-linear order:
// wf[((k*4 + c)*64 + l)*8 + j] = w[co = c*16 + (l&15)][ci = (l>>4)*8 + j][k]
__global__ void prep_w(const float* __restrict__ w, __hip_bfloat16* __restrict__ wf) {
    int idx = blockIdx.x * 256 + threadIdx.x;
    if (idx >= KK * 4 * 64 * 8) return;
    int j = idx & 7;
    int l = (idx >> 3) & 63;
    int c = (idx >> 9) & 3;
    int k = idx >> 11;
    int co = c * 16 + (l & 15);
    int ci = (l >> 4) * 8 + j;
    wf[idx] = __float2bfloat16(w[(co * CIN + ci) * KK + k]);
}

__launch_bounds__(512, 6)
__global__ void dcn3d(const float* __restrict__ x, const float* __restrict__ off,
                      const float* __restrict__ msk, const float* __restrict__ wsrc_f,
                      const __hip_bfloat16* __restrict__ wf,
                      const float* __restrict__ bias, float* __restrict__ out,
                      int use_wf) {
    // block -> (b, d, h)
    int blk = blockIdx.x;
    int h = blk % HH_;
    int t0 = blk / HH_;
    int d = t0 % DD_;
    int b = t0 / DD_;

    // packed bilinear params: x = po00|po01<<16, y = po10|po11<<16,
    //                         z = half2(pw00,pw01), w = half2(pw10,pw11)
    __shared__ uint4 Pp[KK * WW_];        // 20736 B
    __shared__ float Cred[COUT * CP];     // 12544 B

    int tid = threadIdx.x;
    int lane = tid & 63;
    int wid = tid >> 6;

    // ---- Phase A: per-(k, w) bilinear parameters, packed; also zero Cred ----
    for (int e = tid; e < KK * WW_; e += 512) {
        int k = e / WW_;
        int w = e - k * WW_;
        int kd = k / 9, kh = (k / 3) % 3, kw = k % 3;
        int dpos = d + kd - 1;
        bool vd = (dpos >= 0) && (dpos < DD_);
        int didx = min(max(dpos, 0), DD_ - 1);
        int sp = d * HWs + h * WW_ + w;
        int obase = (b * (2 * KK) + 2 * k) * DHW + sp;
        float oh = off[obase];
        float ow = off[obase + DHW];
        float m  = msk[(b * KK + k) * DHW + sp];
        float hh = (float)(kh + h - 1) + oh;
        float ww = (float)(kw + w - 1) + ow;
        float h0f = floorf(hh), w0f = floorf(ww);
        float lh = hh - h0f, lw = ww - w0f;
        int h0 = (int)h0f, w0 = (int)w0f;
        int h1 = h0 + 1, w1 = w0 + 1;
        bool ih0 = (h0 >= 0) && (h0 < HH_);
        bool ih1 = (h1 >= 0) && (h1 < HH_);
        bool iw0 = (w0 >= 0) && (w0 < WW_);
        bool iw1 = (w1 >= 0) && (w1 < WW_);
        int h0c = min(max(h0, 0), HH_ - 1), h1c = min(max(h1, 0), HH_ - 1);
        int w0c = min(max(w0, 0), WW_ - 1), w1c = min(max(w1, 0), WW_ - 1);
        float vm = vd ? m : 0.0f;
        float f00 = (ih0 && iw0) ? (1.0f - lh) * (1.0f - lw) * vm : 0.0f;
        float f01 = (ih0 && iw1) ? (1.0f - lh) * lw * vm : 0.0f;
        float f10 = (ih1 && iw0) ? lh * (1.0f - lw) * vm : 0.0f;
        float f11 = (ih1 && iw1) ? lh * lw * vm : 0.0f;
        int r0 = didx * HWs + h0c * WW_;
        int r1 = didx * HWs + h1c * WW_;
        uint4 P;
        P.x = (unsigned)(r0 + w0c) | ((unsigned)(r0 + w1c) << 16);
        P.y = (unsigned)(r1 + w0c) | ((unsigned)(r1 + w1c) << 16);
        __half2 ha = __floats2half2_rn(f00, f01);
        __half2 hb = __floats2half2_rn(f10, f11);
        P.z = *(const unsigned int*)&ha;
        P.w = *(const unsigned int*)&hb;
        Pp[e] = P;
    }
    for (int e = tid; e < COUT * CP; e += 512) Cred[e] = 0.0f;
    __syncthreads();

    const float* xb = x + b * CIN * DHW;
    int wl = lane & 15;
    int cio = (lane >> 4) * 8;

    f32x4 acc[3][4];   // [w-tile][co-strip] — all indices compile-time after unroll
#pragma unroll
    for (int t = 0; t < 3; ++t)
#pragma unroll
        for (int c = 0; c < 4; ++c) acc[t][c] = (f32x4){0.f, 0.f, 0.f, 0.f};

    // ---- k-split: wave `wid` handles k = wid, wid+8, wid+16, wid+24. No barriers. ----
    for (int k = wid; k < KK; k += 8) {
        // A-fragments, all 4 co-strips
        short8v a[4];
        if (use_wf) {
#pragma unroll
            for (int c = 0; c < 4; ++c)
                a[c] = *(const short8v*)((const short*)wf + ((k * 4 + c) * 64 + lane) * 8);
        } else {
#pragma unroll
            for (int c = 0; c < 4; ++c) {
                int co = c * 16 + (lane & 15);
#pragma unroll
                for (int j = 0; j < 8; ++j) {
                    __hip_bfloat16 hv = __float2bfloat16(wsrc_f[(co * CIN + cio + j) * KK + k]);
                    a[c][j] = *(const short*)&hv;
                }
            }
        }
#pragma unroll
        for (int t = 0; t < 3; ++t) {
            uint4 P = Pp[k * WW_ + wl + 16 * t];
            float2 wa = __half22float2(*(const __half2*)&P.z);
            float2 wb = __half22float2(*(const __half2*)&P.w);
            int i00 = (int)(P.x & 0xFFFFu), i01 = (int)(P.x >> 16);
            int i10 = (int)(P.y & 0xFFFFu), i11 = (int)(P.y >> 16);
            short8v bb;
#pragma unroll
            for (int j = 0; j < 8; ++j) {
                const float* xp = xb + (cio + j) * DHW;
                float v = wa.x * xp[i00] + wa.y * xp[i01]
                        + wb.x * xp[i10] + wb.y * xp[i11];
                __hip_bfloat16 hv = __float2bfloat16(v);
                bb[j] = *(const short*)&hv;
            }
            acc[t][0] = __builtin_amdgcn_mfma_f32_16x16x32_bf16(a[0], bb, acc[t][0], 0, 0, 0);
            acc[t][1] = __builtin_amdgcn_mfma_f32_16x16x32_bf16(a[1], bb, acc[t][1], 0, 0, 0);
            acc[t][2] = __builtin_amdgcn_mfma_f32_16x16x32_bf16(a[2], bb, acc[t][2], 0, 0, 0);
            acc[t][3] = __builtin_amdgcn_mfma_f32_16x16x32_bf16(a[3], bb, acc[t][3], 0, 0, 0);
        }
    }

    // ---- cross-wave reduction via LDS f32 atomics ----
    __syncthreads();   // Cred zeroed in phase A; all waves done with k-loop (Pp reads)
#pragma unroll
    for (int t = 0; t < 3; ++t)
#pragma unroll
        for (int c = 0; c < 4; ++c)
#pragma unroll
            for (int r = 0; r < 4; ++r) {
                int co = c * 16 + (lane >> 4) * 4 + r;
                int w = wl + 16 * t;
                atomicAdd(&Cred[co * CP + w], acc[t][c][r]);
            }
    __syncthreads();

    // ---- store: bias + coalesced ----
    for (int e = tid; e < COUT * WW_; e += 512) {
        int co = e / WW_;
        int w = e - co * WW_;
        out[((b * COUT + co) * DD_ + d) * HWs + h * WW_ + w] = Cred[co * CP + w] + bias[co];
    }
}

extern "C" void kernel_launch(void* const* d_in, const int* in_sizes, int n_in,
                              void* d_out, int out_size, void* d_ws, size_t ws_size,
                              hipStream_t stream) {
    const float* x    = (const float*)d_in[0];
    const float* off  = (const float*)d_in[1];
    const float* msk  = (const float*)d_in[2];
    const float* w    = (const float*)d_in[3];
    const float* bias = (const float*)d_in[4];
    float* out = (float*)d_out;

    const size_t WF_BYTES = (size_t)KK * 4 * 64 * 8 * sizeof(__hip_bfloat16); // 110592
    int use_wf = (ws_size >= WF_BYTES) ? 1 : 0;
    __hip_bfloat16* wf = (__hip_bfloat16*)d_ws;
    if (use_wf) {
        prep_w<<<(KK * 4 * 64 * 8 + 255) / 256, 256, 0, stream>>>(w, wf);
    }
    dcn3d<<<BSZ * DD_ * HH_, 512, 0, stream>>>(x, off, msk, w, wf, bias, out, use_wf);
}

// Round 4
// 158.439 us; speedup vs baseline: 1.5556x; 1.5556x over previous
//
#include <hip/hip_runtime.h>
#include <hip/hip_bf16.h>
#include <hip/hip_fp16.h>

#define BSZ 2
#define CIN 32
#define COUT 64
#define DD_ 8
#define HH_ 48
#define WW_ 48
#define KK 27
#define HWs (HH_*WW_)
#define DHW (DD_*HH_*WW_)
#define CP 49   // padded C-reduce row stride (floats)

typedef __attribute__((ext_vector_type(8))) short short8v;
typedef __attribute__((ext_vector_type(4))) float f32x4;

// Pack weight (Cout, Cin, K) fp32 -> bf16 A-fragments in lane-linear order:
// wf[((k*4 + c)*64 + l)*8 + j] = w[co = c*16 + (l&15)][ci = (l>>4)*8 + j][k]
__global__ void prep_w(const float* __restrict__ w, __hip_bfloat16* __restrict__ wf) {
    int idx = blockIdx.x * 256 + threadIdx.x;
    if (idx >= KK * 4 * 64 * 8) return;
    int j = idx & 7;
    int l = (idx >> 3) & 63;
    int c = (idx >> 9) & 3;
    int k = idx >> 11;
    int co = c * 16 + (l & 15);
    int ci = (l >> 4) * 8 + j;
    wf[idx] = __float2bfloat16(w[(co * CIN + ci) * KK + k]);
}

__launch_bounds__(512, 2)
__global__ void dcn3d(const float* __restrict__ x, const float* __restrict__ off,
                      const float* __restrict__ msk, const float* __restrict__ wsrc_f,
                      const __hip_bfloat16* __restrict__ wf,
                      const float* __restrict__ bias, float* __restrict__ out,
                      int use_wf) {
    // block -> (b, d, h)
    int blk = blockIdx.x;
    int h = blk % HH_;
    int t0 = blk / HH_;
    int d = t0 % DD_;
    int b = t0 / DD_;

    // packed bilinear params: x = po00|po01<<16, y = po10|po11<<16,
    //                         z = half2(pw00,pw01), w = half2(pw10,pw11)
    __shared__ uint4 Pp[KK * WW_];        // 20736 B
    __shared__ float Cred[COUT * CP];     // 12544 B

    int tid = threadIdx.x;
    int lane = tid & 63;
    int wid = tid >> 6;

    // ---- Phase A: per-(k, w) bilinear parameters, packed; also zero Cred ----
    for (int e = tid; e < KK * WW_; e += 512) {
        int k = e / WW_;
        int w = e - k * WW_;
        int kd = k / 9, kh = (k / 3) % 3, kw = k % 3;
        int dpos = d + kd - 1;
        bool vd = (dpos >= 0) && (dpos < DD_);
        int didx = min(max(dpos, 0), DD_ - 1);
        int sp = d * HWs + h * WW_ + w;
        int obase = (b * (2 * KK) + 2 * k) * DHW + sp;
        float oh = off[obase];
        float ow = off[obase + DHW];
        float m  = msk[(b * KK + k) * DHW + sp];
        float hh = (float)(kh + h - 1) + oh;
        float ww = (float)(kw + w - 1) + ow;
        float h0f = floorf(hh), w0f = floorf(ww);
        float lh = hh - h0f, lw = ww - w0f;
        int h0 = (int)h0f, w0 = (int)w0f;
        int h1 = h0 + 1, w1 = w0 + 1;
        bool ih0 = (h0 >= 0) && (h0 < HH_);
        bool ih1 = (h1 >= 0) && (h1 < HH_);
        bool iw0 = (w0 >= 0) && (w0 < WW_);
        bool iw1 = (w1 >= 0) && (w1 < WW_);
        int h0c = min(max(h0, 0), HH_ - 1), h1c = min(max(h1, 0), HH_ - 1);
        int w0c = min(max(w0, 0), WW_ - 1), w1c = min(max(w1, 0), WW_ - 1);
        float vm = vd ? m : 0.0f;
        float f00 = (ih0 && iw0) ? (1.0f - lh) * (1.0f - lw) * vm : 0.0f;
        float f01 = (ih0 && iw1) ? (1.0f - lh) * lw * vm : 0.0f;
        float f10 = (ih1 && iw0) ? lh * (1.0f - lw) * vm : 0.0f;
        float f11 = (ih1 && iw1) ? lh * lw * vm : 0.0f;
        int r0 = didx * HWs + h0c * WW_;
        int r1 = didx * HWs + h1c * WW_;
        uint4 P;
        P.x = (unsigned)(r0 + w0c) | ((unsigned)(r0 + w1c) << 16);
        P.y = (unsigned)(r1 + w0c) | ((unsigned)(r1 + w1c) << 16);
        __half2 ha = __floats2half2_rn(f00, f01);
        __half2 hb = __floats2half2_rn(f10, f11);
        P.z = *(const unsigned int*)&ha;
        P.w = *(const unsigned int*)&hb;
        Pp[e] = P;
    }
    for (int e = tid; e < COUT * CP; e += 512) Cred[e] = 0.0f;
    __syncthreads();

    const float* xb = x + b * CIN * DHW;
    int wl = lane & 15;
    int cio = (lane >> 4) * 8;

    f32x4 acc00 = {0.f, 0.f, 0.f, 0.f};
    f32x4 acc01 = acc00, acc02 = acc00, acc03 = acc00;
    f32x4 acc10 = acc00, acc11 = acc00, acc12 = acc00, acc13 = acc00;
    f32x4 acc20 = acc00, acc21 = acc00, acc22 = acc00, acc23 = acc00;

    // ---- k-split: wave `wid` handles k = wid, wid+8, wid+16(, wid+24). No barriers. ----
    for (int k = wid; k < KK; k += 8) {
        short8v a0, a1, a2, a3;
        if (use_wf) {
            const short* wp = (const short*)wf + ((k * 4) * 64 + lane) * 8;
            a0 = *(const short8v*)(wp + 0 * 64 * 8);
            a1 = *(const short8v*)(wp + 1 * 64 * 8);
            a2 = *(const short8v*)(wp + 2 * 64 * 8);
            a3 = *(const short8v*)(wp + 3 * 64 * 8);
        } else {
            short8v at[4];
#pragma unroll
            for (int c = 0; c < 4; ++c) {
                int co = c * 16 + (lane & 15);
#pragma unroll
                for (int j = 0; j < 8; ++j) {
                    __hip_bfloat16 hv = __float2bfloat16(wsrc_f[(co * CIN + cio + j) * KK + k]);
                    at[c][j] = *(const short*)&hv;
                }
            }
            a0 = at[0]; a1 = at[1]; a2 = at[2]; a3 = at[3];
        }

#define TSTEP(T, A0, A1, A2, A3)                                               \
        {                                                                      \
            uint4 P = Pp[k * WW_ + wl + 16 * T];                               \
            float2 wa = __half22float2(*(const __half2*)&P.z);                 \
            float2 wb = __half22float2(*(const __half2*)&P.w);                 \
            int i00 = (int)(P.x & 0xFFFFu), i01 = (int)(P.x >> 16);            \
            int i10 = (int)(P.y & 0xFFFFu), i11 = (int)(P.y >> 16);            \
            short8v bb;                                                        \
            _Pragma("unroll")                                                  \
            for (int j = 0; j < 8; ++j) {                                      \
                const float* xp = xb + (cio + j) * DHW;                        \
                float v = wa.x * xp[i00] + wa.y * xp[i01]                      \
                        + wb.x * xp[i10] + wb.y * xp[i11];                     \
                __hip_bfloat16 hv = __float2bfloat16(v);                       \
                bb[j] = *(const short*)&hv;                                    \
            }                                                                  \
            A0 = __builtin_amdgcn_mfma_f32_16x16x32_bf16(a0, bb, A0, 0, 0, 0); \
            A1 = __builtin_amdgcn_mfma_f32_16x16x32_bf16(a1, bb, A1, 0, 0, 0); \
            A2 = __builtin_amdgcn_mfma_f32_16x16x32_bf16(a2, bb, A2, 0, 0, 0); \
            A3 = __builtin_amdgcn_mfma_f32_16x16x32_bf16(a3, bb, A3, 0, 0, 0); \
        }

        TSTEP(0, acc00, acc01, acc02, acc03)
        TSTEP(1, acc10, acc11, acc12, acc13)
        TSTEP(2, acc20, acc21, acc22, acc23)
#undef TSTEP
    }

    // ---- cross-wave reduction via LDS f32 atomics (Cred zeroed before barrier 1) ----
    int rrow = (lane >> 4) * 4;
#define RED(T, C, ACC)                                                         \
    _Pragma("unroll")                                                          \
    for (int r = 0; r < 4; ++r)                                                \
        atomicAdd(&Cred[(C * 16 + rrow + r) * CP + wl + 16 * T], ACC[r]);
    RED(0, 0, acc00) RED(0, 1, acc01) RED(0, 2, acc02) RED(0, 3, acc03)
    RED(1, 0, acc10) RED(1, 1, acc11) RED(1, 2, acc12) RED(1, 3, acc13)
    RED(2, 0, acc20) RED(2, 1, acc21) RED(2, 2, acc22) RED(2, 3, acc23)
#undef RED
    __syncthreads();

    // ---- store: bias + coalesced ----
    for (int e = tid; e < COUT * WW_; e += 512) {
        int co = e / WW_;
        int w = e - co * WW_;
        out[((b * COUT + co) * DD_ + d) * HWs + h * WW_ + w] = Cred[co * CP + w] + bias[co];
    }
}

extern "C" void kernel_launch(void* const* d_in, const int* in_sizes, int n_in,
                              void* d_out, int out_size, void* d_ws, size_t ws_size,
                              hipStream_t stream) {
    const float* x    = (const float*)d_in[0];
    const float* off  = (const float*)d_in[1];
    const float* msk  = (const float*)d_in[2];
    const float* w    = (const float*)d_in[3];
    const float* bias = (const float*)d_in[4];
    float* out = (float*)d_out;

    const size_t WF_BYTES = (size_t)KK * 4 * 64 * 8 * sizeof(__hip_bfloat16); // 110592
    int use_wf = (ws_size >= WF_BYTES) ? 1 : 0;
    __hip_bfloat16* wf = (__hip_bfloat16*)d_ws;
    if (use_wf) {
        prep_w<<<(KK * 4 * 64 * 8 + 255) / 256, 256, 0, stream>>>(w, wf);
    }
    dcn3d<<<BSZ * DD_ * HH_, 512, 0, stream>>>(x, off, msk, w, wf, bias, out, use_wf);
}

// Round 5
// 149.542 us; speedup vs baseline: 1.6481x; 1.0595x over previous
//
#include <hip/hip_runtime.h>
#include <hip/hip_bf16.h>
#include <hip/hip_fp16.h>

#define BSZ 2
#define CIN 32
#define COUT 64
#define DD_ 8
#define HH_ 48
#define WW_ 48
#define KK 27
#define HWs (HH_*WW_)
#define DHW (DD_*HH_*WW_)
#define CP 49    // padded C-reduce row stride (floats)
#define NT 576   // 9 waves: perfect 27/9 k-split

typedef __attribute__((ext_vector_type(8))) short short8v;
typedef __attribute__((ext_vector_type(4))) float f32x4;

__device__ __forceinline__ float b2f(short s) {
    union { unsigned u; float f; } c;
    c.u = ((unsigned)(unsigned short)s) << 16;
    return c.f;
}

// Pack weight (Cout, Cin, K) fp32 -> bf16 A-fragments in lane-linear order:
// wf[((k*4 + c)*64 + l)*8 + j] = w[co = c*16 + (l&15)][ci = (l>>4)*8 + j][k]
__global__ void prep_w(const float* __restrict__ w, __hip_bfloat16* __restrict__ wf) {
    int idx = blockIdx.x * 256 + threadIdx.x;
    if (idx >= KK * 4 * 64 * 8) return;
    int j = idx & 7;
    int l = (idx >> 3) & 63;
    int c = (idx >> 9) & 3;
    int k = idx >> 11;
    int co = c * 16 + (l & 15);
    int ci = (l >> 4) * 8 + j;
    wf[idx] = __float2bfloat16(w[(co * CIN + ci) * KK + k]);
}

// x [B][Cin][D][H][W] fp32 -> xT [B][D][H][W][Cin] bf16 (channels-last), via LDS transpose.
__global__ void prep_xt(const float* __restrict__ x, __hip_bfloat16* __restrict__ xT) {
    __shared__ float tile[CIN][WW_];
    int blk = blockIdx.x;
    int h = blk % HH_;
    int t0 = blk / HH_;
    int d = t0 % DD_;
    int b = t0 / DD_;
    int base = d * HWs + h * WW_;
    for (int e = threadIdx.x; e < CIN * WW_; e += 256) {
        int ci = e / WW_, w = e - ci * WW_;
        tile[ci][w] = x[(b * CIN + ci) * DHW + base + w];
    }
    __syncthreads();
    for (int e = threadIdx.x; e < CIN * WW_; e += 256) {
        int w = e >> 5, ci = e & 31;
        xT[(size_t)(b * DHW + base + w) * CIN + ci] = __float2bfloat16(tile[ci][w]);
    }
}

template<int USE_XT>
__launch_bounds__(NT, 4)
__global__ void dcn3d(const float* __restrict__ x, const __hip_bfloat16* __restrict__ xT,
                      const float* __restrict__ off, const float* __restrict__ msk,
                      const float* __restrict__ wsrc_f, const __hip_bfloat16* __restrict__ wf,
                      const float* __restrict__ bias, float* __restrict__ out, int use_wf) {
    // block -> (b, d, h)
    int blk = blockIdx.x;
    int h = blk % HH_;
    int t0 = blk / HH_;
    int d = t0 % DD_;
    int b = t0 / DD_;

    __shared__ float Cred[COUT * CP];   // 12544 B

    int tid = threadIdx.x;
    int lane = tid & 63;
    int wid = tid >> 6;          // 0..8
    int wl = lane & 15;
    int cio = (lane >> 4) * 8;

    for (int e = tid; e < COUT * CP; e += NT) Cred[e] = 0.0f;
    __syncthreads();

    const float* xb = x + b * CIN * DHW;                       // USE_XT=0 path
    const short* xTb = (const short*)xT + (size_t)b * DHW * CIN;

    f32x4 acc00 = {0.f, 0.f, 0.f, 0.f};
    f32x4 acc01 = acc00, acc02 = acc00, acc03 = acc00;
    f32x4 acc10 = acc00, acc11 = acc00, acc12 = acc00, acc13 = acc00;
    f32x4 acc20 = acc00, acc21 = acc00, acc22 = acc00, acc23 = acc00;

    int spbase = d * HWs + h * WW_;

#pragma unroll 1
    for (int ki = 0; ki < 3; ++ki) {
        int k = wid + 9 * ki;                 // wave-uniform
        int kd = k / 9, kh = (k / 3) % 3, kw = k % 3;
        int dpos = d + kd - 1;
        bool vd = (dpos >= 0) && (dpos < DD_);
        int didx = min(max(dpos, 0), DD_ - 1);
        int rbase = didx * HWs;

        // A-fragments for this k (all 4 co-strips)
        short8v a0, a1, a2, a3;
        if (USE_XT || use_wf) {
            const short* wp = (const short*)wf + ((k * 4) * 64 + lane) * 8;
            a0 = *(const short8v*)(wp + 0 * 512);
            a1 = *(const short8v*)(wp + 1 * 512);
            a2 = *(const short8v*)(wp + 2 * 512);
            a3 = *(const short8v*)(wp + 3 * 512);
        } else {
            short8v at[4];
#pragma unroll
            for (int c = 0; c < 4; ++c) {
                int co = c * 16 + (lane & 15);
#pragma unroll
                for (int j = 0; j < 8; ++j) {
                    __hip_bfloat16 hv = __float2bfloat16(wsrc_f[(co * CIN + cio + j) * KK + k]);
                    at[c][j] = *(const short*)&hv;
                }
            }
            a0 = at[0]; a1 = at[1]; a2 = at[2]; a3 = at[3];
        }

#define TSTEP(T, A0, A1, A2, A3)                                               \
        {                                                                      \
            int w = wl + 16 * T;                                               \
            int sp = spbase + w;                                               \
            float oh = off[(b * (2 * KK) + 2 * k) * DHW + sp];                 \
            float ow = off[(b * (2 * KK) + 2 * k + 1) * DHW + sp];             \
            float m  = msk[(b * KK + k) * DHW + sp];                           \
            float vm = vd ? m : 0.0f;                                          \
            float hh = (float)(kh + h - 1) + oh;                               \
            float ww = (float)(kw + w - 1) + ow;                               \
            float h0f = floorf(hh), w0f = floorf(ww);                          \
            float lh = hh - h0f, lw = ww - w0f;                                \
            int h0 = (int)h0f, w0 = (int)w0f;                                  \
            int h1 = h0 + 1, w1 = w0 + 1;                                      \
            bool ih0 = (h0 >= 0) && (h0 < HH_);                                \
            bool ih1 = (h1 >= 0) && (h1 < HH_);                                \
            bool iw0 = (w0 >= 0) && (w0 < WW_);                                \
            bool iw1 = (w1 >= 0) && (w1 < WW_);                                \
            int h0c = min(max(h0, 0), HH_ - 1), h1c = min(max(h1, 0), HH_ - 1);\
            int w0c = min(max(w0, 0), WW_ - 1), w1c = min(max(w1, 0), WW_ - 1);\
            float f00 = (ih0 && iw0) ? (1.0f - lh) * (1.0f - lw) * vm : 0.0f;  \
            float f01 = (ih0 && iw1) ? (1.0f - lh) * lw * vm : 0.0f;           \
            float f10 = (ih1 && iw0) ? lh * (1.0f - lw) * vm : 0.0f;           \
            float f11 = (ih1 && iw1) ? lh * lw * vm : 0.0f;                    \
            int sp00 = rbase + h0c * WW_ + w0c;                                \
            int sp01 = rbase + h0c * WW_ + w1c;                                \
            int sp10 = rbase + h1c * WW_ + w0c;                                \
            int sp11 = rbase + h1c * WW_ + w1c;                                \
            short8v bb;                                                        \
            if (USE_XT) {                                                      \
                short8v c00 = *(const short8v*)(xTb + (sp00 << 5) + cio);      \
                short8v c01 = *(const short8v*)(xTb + (sp01 << 5) + cio);      \
                short8v c10 = *(const short8v*)(xTb + (sp10 << 5) + cio);      \
                short8v c11 = *(const short8v*)(xTb + (sp11 << 5) + cio);      \
                _Pragma("unroll")                                              \
                for (int j = 0; j < 8; ++j) {                                  \
                    float v = f00 * b2f(c00[j]) + f01 * b2f(c01[j])            \
                            + f10 * b2f(c10[j]) + f11 * b2f(c11[j]);           \
                    __hip_bfloat16 hv = __float2bfloat16(v);                   \
                    bb[j] = *(const short*)&hv;                                \
                }                                                              \
            } else {                                                           \
                _Pragma("unroll")                                              \
                for (int j = 0; j < 8; ++j) {                                  \
                    const float* xp = xb + (cio + j) * DHW;                    \
                    float v = f00 * xp[sp00] + f01 * xp[sp01]                  \
                            + f10 * xp[sp10] + f11 * xp[sp11];                 \
                    __hip_bfloat16 hv = __float2bfloat16(v);                   \
                    bb[j] = *(const short*)&hv;                                \
                }                                                              \
            }                                                                  \
            A0 = __builtin_amdgcn_mfma_f32_16x16x32_bf16(a0, bb, A0, 0, 0, 0); \
            A1 = __builtin_amdgcn_mfma_f32_16x16x32_bf16(a1, bb, A1, 0, 0, 0); \
            A2 = __builtin_amdgcn_mfma_f32_16x16x32_bf16(a2, bb, A2, 0, 0, 0); \
            A3 = __builtin_amdgcn_mfma_f32_16x16x32_bf16(a3, bb, A3, 0, 0, 0); \
        }

        TSTEP(0, acc00, acc01, acc02, acc03)
        TSTEP(1, acc10, acc11, acc12, acc13)
        TSTEP(2, acc20, acc21, acc22, acc23)
#undef TSTEP
    }

    // ---- cross-wave reduction via LDS f32 atomics ----
    int rrow = (lane >> 4) * 4;
#define RED(T, C, ACC)                                                         \
    _Pragma("unroll")                                                          \
    for (int r = 0; r < 4; ++r)                                                \
        atomicAdd(&Cred[(C * 16 + rrow + r) * CP + wl + 16 * T], ACC[r]);
    RED(0, 0, acc00) RED(0, 1, acc01) RED(0, 2, acc02) RED(0, 3, acc03)
    RED(1, 0, acc10) RED(1, 1, acc11) RED(1, 2, acc12) RED(1, 3, acc13)
    RED(2, 0, acc20) RED(2, 1, acc21) RED(2, 2, acc22) RED(2, 3, acc23)
#undef RED
    __syncthreads();

    // ---- store: bias + coalesced ----
    for (int e = tid; e < COUT * WW_; e += NT) {
        int co = e / WW_;
        int w = e - co * WW_;
        out[((b * COUT + co) * DD_ + d) * HWs + h * WW_ + w] = Cred[co * CP + w] + bias[co];
    }
}

extern "C" void kernel_launch(void* const* d_in, const int* in_sizes, int n_in,
                              void* d_out, int out_size, void* d_ws, size_t ws_size,
                              hipStream_t stream) {
    const float* x    = (const float*)d_in[0];
    const float* off  = (const float*)d_in[1];
    const float* msk  = (const float*)d_in[2];
    const float* w    = (const float*)d_in[3];
    const float* bias = (const float*)d_in[4];
    float* out = (float*)d_out;

    const size_t WF_BYTES = (size_t)KK * 4 * 64 * 8 * sizeof(__hip_bfloat16); // 110592
    const size_t XT_OFF   = 131072;
    const size_t XT_BYTES = (size_t)BSZ * DHW * CIN * sizeof(__hip_bfloat16); // 2359296

    int use_wf = (ws_size >= WF_BYTES) ? 1 : 0;
    int use_xt = (ws_size >= XT_OFF + XT_BYTES) ? 1 : 0;
    __hip_bfloat16* wf = (__hip_bfloat16*)d_ws;
    __hip_bfloat16* xT = (__hip_bfloat16*)((char*)d_ws + XT_OFF);

    if (use_wf) {
        prep_w<<<(KK * 4 * 64 * 8 + 255) / 256, 256, 0, stream>>>(w, wf);
    }
    if (use_wf && use_xt) {
        prep_xt<<<BSZ * DD_ * HH_, 256, 0, stream>>>(x, xT);
        dcn3d<1><<<BSZ * DD_ * HH_, NT, 0, stream>>>(x, xT, off, msk, w, wf, bias, out, 1);
    } else {
        dcn3d<0><<<BSZ * DD_ * HH_, NT, 0, stream>>>(x, xT, off, msk, w, wf, bias, out, use_wf);
    }
}

// Round 6
// 43.505 us; speedup vs baseline: 5.6651x; 3.4374x over previous
//
#include <hip/hip_runtime.h>
#include <hip/hip_bf16.h>
#include <hip/hip_fp16.h>

#define BSZ 2
#define CIN 32
#define COUT 64
#define DD_ 8
#define HH_ 48
#define WW_ 48
#define KK 27
#define HWs (HH_*WW_)
#define DHW (DD_*HH_*WW_)
#define NT 768        // 12 waves = 12 output tiles (4 co-strips x 3 w-tiles)
#define NBLK (BSZ*DD_*HH_)

typedef __attribute__((ext_vector_type(8))) _Float16 half8;
typedef __attribute__((ext_vector_type(4))) float f32x4;

// Combined prep:
//  blocks [0, NBLK):          x [B][Cin][D][H][W] f32 -> xT [B][D][H][W][Cin] f16
//  blocks [NBLK, NBLK+216):   w (Cout,Cin,K) f32 -> wf f16 A-fragments, lane-linear:
//                             wf[((k*4 + c)*64 + l)*8 + j] = w[c*16+(l&15)][(l>>4)*8+j][k]
__global__ void prep(const float* __restrict__ x, const float* __restrict__ wsrc,
                     _Float16* __restrict__ xT, _Float16* __restrict__ wf) {
    __shared__ float tile[CIN][WW_];
    int blk = blockIdx.x;
    if (blk < NBLK) {
        int h = blk % HH_;
        int t0 = blk / HH_;
        int d = t0 % DD_;
        int b = t0 / DD_;
        int base = d * HWs + h * WW_;
        for (int e = threadIdx.x; e < CIN * WW_; e += 256) {
            int ci = e / WW_, w = e - ci * WW_;
            tile[ci][w] = x[(size_t)(b * CIN + ci) * DHW + base + w];
        }
        __syncthreads();
        for (int e = threadIdx.x; e < CIN * WW_; e += 256) {
            int w = e >> 5, ci = e & 31;
            xT[(size_t)(b * DHW + base + w) * CIN + ci] = (_Float16)tile[ci][w];
        }
    } else {
        int idx = (blk - NBLK) * 256 + threadIdx.x;
        if (idx < KK * 4 * 64 * 8) {
            int j = idx & 7, l = (idx >> 3) & 63, c = (idx >> 9) & 3, k = idx >> 11;
            int co = c * 16 + (l & 15), ci = (l >> 4) * 8 + j;
            wf[idx] = (_Float16)wsrc[(co * CIN + ci) * KK + k];
        }
    }
}

#define SPLAT8(H) {H, H, H, H, H, H, H, H}

template<int USE_XT>
__launch_bounds__(NT, 4)
__global__ void dcn3d(const float* __restrict__ x, const _Float16* __restrict__ xT,
                      const float* __restrict__ off, const float* __restrict__ msk,
                      const float* __restrict__ wsrc, const _Float16* __restrict__ wf,
                      const float* __restrict__ bias, float* __restrict__ out) {
    int blk = blockIdx.x;
    int h = blk % HH_;
    int t0 = blk / HH_;
    int d = t0 % DD_;
    int b = t0 / DD_;

    // S half-tile in MFMA-B-fragment order, 16B granules:
    // granule index = (kl*3 + T)*64 + g*16 + wl   (w = T*16+wl, ci-chunk g)
    __shared__ half8 Sh[14 * 3 * 4 * 16];   // 43008 B

    int tid = threadIdx.x;
    int lane = tid & 63;
    int wid = tid >> 6;
    int cstrip = wid & 3;      // co strip (0..3)
    int T = wid >> 2;          // w tile (0..2)
    int spb = d * HWs + h * WW_;

    const _Float16* xTb = xT + (size_t)b * DHW * CIN;
    const float* xb = x + (size_t)b * CIN * DHW;

    // ---- pre-phase: params for both k-halves, all off/msk loads issued here ----
#define PREP(HF, NK, KB)                                                        \
    int sp00_##HF = 0, sp01_##HF = 0, sp10_##HF = 0, sp11_##HF = 0;             \
    float f00_##HF = 0.f, f01_##HF = 0.f, f10_##HF = 0.f, f11_##HF = 0.f;       \
    if (tid < (NK) * 48) {                                                      \
        int kl = tid / 48;                                                      \
        int w = tid - kl * 48;                                                  \
        int k = (KB) + kl;                                                      \
        int kd = k / 9, kh2 = (k / 3) % 3, kw2 = k % 3;                         \
        int dpos = d + kd - 1;                                                  \
        bool vd = (dpos >= 0) && (dpos < DD_);                                  \
        int didx = min(max(dpos, 0), DD_ - 1);                                  \
        int rb = didx * HWs;                                                    \
        int sp = spb + w;                                                       \
        float oh = off[(b * (2 * KK) + 2 * k) * DHW + sp];                      \
        float ow = off[(b * (2 * KK) + 2 * k + 1) * DHW + sp];                  \
        float m  = msk[(b * KK + k) * DHW + sp];                                \
        float vm = vd ? m : 0.f;                                                \
        float hhf = (float)(kh2 + h - 1) + oh;                                  \
        float wwf = (float)(kw2 + w - 1) + ow;                                  \
        float h0f = floorf(hhf), w0f = floorf(wwf);                             \
        float lh = hhf - h0f, lw = wwf - w0f;                                   \
        int h0 = (int)h0f, w0 = (int)w0f, h1 = h0 + 1, w1 = w0 + 1;             \
        bool ih0 = (h0 >= 0) && (h0 < HH_), ih1 = (h1 >= 0) && (h1 < HH_);      \
        bool iw0 = (w0 >= 0) && (w0 < WW_), iw1 = (w1 >= 0) && (w1 < WW_);      \
        int h0c = min(max(h0, 0), HH_ - 1), h1c = min(max(h1, 0), HH_ - 1);     \
        int w0c = min(max(w0, 0), WW_ - 1), w1c = min(max(w1, 0), WW_ - 1);     \
        f00_##HF = (ih0 && iw0) ? (1.f - lh) * (1.f - lw) * vm : 0.f;           \
        f01_##HF = (ih0 && iw1) ? (1.f - lh) * lw * vm : 0.f;                   \
        f10_##HF = (ih1 && iw0) ? lh * (1.f - lw) * vm : 0.f;                   \
        f11_##HF = (ih1 && iw1) ? lh * lw * vm : 0.f;                           \
        sp00_##HF = rb + h0c * WW_ + w0c;                                       \
        sp01_##HF = rb + h0c * WW_ + w1c;                                       \
        sp10_##HF = rb + h1c * WW_ + w0c;                                       \
        sp11_##HF = rb + h1c * WW_ + w1c;                                       \
    }

    PREP(0, 14, 0)
    PREP(1, 13, 14)

    // ---- burst sampling: 16 independent dwordx4 gathers/thread, blend, LDS-write ----
#define SAMPLE(HF, NK)                                                          \
    if (tid < (NK) * 48) {                                                      \
        int kl = tid / 48;                                                      \
        int w = tid - kl * 48;                                                  \
        int sb = (kl * 3 + (w >> 4)) * 64 + (w & 15);                           \
        if (USE_XT) {                                                           \
            _Float16 e00 = (_Float16)f00_##HF, e01 = (_Float16)f01_##HF;        \
            _Float16 e10 = (_Float16)f10_##HF, e11 = (_Float16)f11_##HF;        \
            half8 v00 = SPLAT8(e00), v01 = SPLAT8(e01);                         \
            half8 v10 = SPLAT8(e10), v11 = SPLAT8(e11);                         \
            const half8* p00 = (const half8*)(xTb + ((size_t)sp00_##HF << 5));  \
            const half8* p01 = (const half8*)(xTb + ((size_t)sp01_##HF << 5));  \
            const half8* p10 = (const half8*)(xTb + ((size_t)sp10_##HF << 5));  \
            const half8* p11 = (const half8*)(xTb + ((size_t)sp11_##HF << 5));  \
            _Pragma("unroll")                                                   \
            for (int g = 0; g < 4; ++g)                                         \
                Sh[sb + g * 16] = p00[g] * v00 + p01[g] * v01                   \
                                + p10[g] * v10 + p11[g] * v11;                  \
        } else {                                                                \
            _Pragma("unroll")                                                   \
            for (int g = 0; g < 4; ++g) {                                       \
                half8 cv;                                                       \
                _Pragma("unroll")                                               \
                for (int j = 0; j < 8; ++j) {                                   \
                    const float* xp = xb + (size_t)(g * 8 + j) * DHW;           \
                    float v = f00_##HF * xp[sp00_##HF] + f01_##HF * xp[sp01_##HF] \
                            + f10_##HF * xp[sp10_##HF] + f11_##HF * xp[sp11_##HF]; \
                    cv[j] = (_Float16)v;                                        \
                }                                                               \
                Sh[sb + g * 16] = cv;                                           \
            }                                                                   \
        }                                                                       \
    }

    f32x4 acc = {0.f, 0.f, 0.f, 0.f};

    // ---- GEMM phase: wave (cstrip,T) tile, 1 MFMA per k ----
#define GEMM(NK, KB)                                                            \
    _Pragma("unroll 7")                                                         \
    for (int kl = 0; kl < (NK); ++kl) {                                         \
        half8 a;                                                                \
        if (USE_XT) {                                                           \
            a = *(const half8*)(wf + ((((KB) + kl) * 4 + cstrip) * 64 + lane) * 8); \
        } else {                                                                \
            int co = cstrip * 16 + (lane & 15);                                 \
            int ci0 = (lane >> 4) * 8;                                          \
            _Pragma("unroll")                                                   \
            for (int j = 0; j < 8; ++j)                                         \
                a[j] = (_Float16)wsrc[(co * CIN + ci0 + j) * KK + (KB) + kl];   \
        }                                                                       \
        half8 bf = Sh[(kl * 3 + T) * 64 + (lane >> 4) * 16 + (lane & 15)];      \
        acc = __builtin_amdgcn_mfma_f32_16x16x32_f16(a, bf, acc, 0, 0, 0);      \
    }

    SAMPLE(0, 14)
    __syncthreads();
    GEMM(14, 0)
    __syncthreads();
    SAMPLE(1, 13)
    __syncthreads();
    GEMM(13, 14)

    // ---- epilogue: direct store (C: col=lane&15 -> w, row=(lane>>4)*4+r -> co) ----
    int co0 = cstrip * 16 + (lane >> 4) * 4;
    int wcol = T * 16 + (lane & 15);
#pragma unroll
    for (int r = 0; r < 4; ++r)
        out[((b * COUT + co0 + r) * DD_ + d) * HWs + h * WW_ + wcol] = acc[r] + bias[co0 + r];

#undef PREP
#undef SAMPLE
#undef GEMM
}

extern "C" void kernel_launch(void* const* d_in, const int* in_sizes, int n_in,
                              void* d_out, int out_size, void* d_ws, size_t ws_size,
                              hipStream_t stream) {
    const float* x    = (const float*)d_in[0];
    const float* off  = (const float*)d_in[1];
    const float* msk  = (const float*)d_in[2];
    const float* w    = (const float*)d_in[3];
    const float* bias = (const float*)d_in[4];
    float* out = (float*)d_out;

    const size_t WF_BYTES = (size_t)KK * 4 * 64 * 8 * sizeof(_Float16);   // 110592
    const size_t XT_OFF   = 131072;
    const size_t XT_BYTES = (size_t)BSZ * DHW * CIN * sizeof(_Float16);   // 2359296

    _Float16* wf = (_Float16*)d_ws;
    _Float16* xT = (_Float16*)((char*)d_ws + XT_OFF);
    int use = (ws_size >= XT_OFF + XT_BYTES && WF_BYTES <= XT_OFF) ? 1 : 0;

    if (use) {
        int wblocks = (KK * 4 * 64 * 8 + 255) / 256;   // 216
        prep<<<NBLK + wblocks, 256, 0, stream>>>(x, w, xT, wf);
        dcn3d<1><<<NBLK, NT, 0, stream>>>(x, xT, off, msk, w, wf, bias, out);
    } else {
        dcn3d<0><<<NBLK, NT, 0, stream>>>(x, xT, off, msk, w, wf, bias, out);
    }
}